// Round 2
// baseline (916.250 us; speedup 1.0000x reference)
//
#include <hip/hip_runtime.h>
#include <hip/hip_bf16.h>

// Model dims
#define NN 2048
#define DS 64
#define DI 256
#define DV 64
#define KK 512
#define HH 4
#define HD 16
#define BB 2
#define TT 4
#define DCAT 192

typedef unsigned long long ull;

__device__ __forceinline__ float wave_sum(float v) {
#pragma unroll
    for (int o = 32; o > 0; o >>= 1) v += __shfl_xor(v, o);
    return v;
}
__device__ __forceinline__ float wave_max(float v) {
#pragma unroll
    for (int o = 32; o > 0; o >>= 1) v = fmaxf(v, __shfl_xor(v, o));
    return v;
}

// ---------------------------------------------------------------- K1: top-k (bitonic) + xproj
// gate[] is precomputed (memset zeros at t=0; pool kernel writes it for t>0).
__global__ __launch_bounds__(1024) void k_topk(
    const float* __restrict__ gate, const float* __restrict__ x,
    const float* __restrict__ W_in, int* __restrict__ col2slot,
    int* __restrict__ act_idx, float* __restrict__ xproj, int t)
{
    int b = blockIdx.x, tid = threadIdx.x;
    __shared__ ull keys[NN];
    __shared__ int slots[NN];
    if (tid < DS) {                        // xproj: x_t @ W_in.T
        const float* xp = x + (b * TT + t) * DI;
        const float* wr = W_in + tid * DI;
        float acc = 0.f;
#pragma unroll 4
        for (int i = 0; i < DI; i++) acc += xp[i] * wr[i];
        xproj[b * DS + tid] = acc;
    }
    for (int i = tid; i < NN; i += 1024) {
        float g = gate[b * NN + i];
        unsigned u = __float_as_uint(g);
        u = (u & 0x80000000u) ? ~u : (u | 0x80000000u);
        keys[i] = ((ull)u << 32) | (unsigned)(NN - 1 - i);
        slots[i] = -1;
    }
    __syncthreads();
    for (int k = 2; k <= NN; k <<= 1) {
        for (int j = k >> 1; j > 0; j >>= 1) {
            for (int base = 0; base < NN; base += 1024) {
                int i = base + tid, ixj = i ^ j;
                if (ixj > i) {
                    ull a = keys[i], c = keys[ixj];
                    bool up = ((i & k) == 0);
                    if ((a > c) == up) { keys[i] = c; keys[ixj] = a; }
                }
            }
            __syncthreads();
        }
    }
    if (tid < KK) {
        int pos = NN - 1 - tid;                       // tid-th largest
        int n = NN - 1 - (int)(keys[pos] & 0xFFFFFFFFu);
        act_idx[b * KK + tid] = n;
        slots[n] = tid;
    }
    __syncthreads();
    for (int i = tid; i < NN; i += 1024) col2slot[b * NN + i] = slots[i];
}

// ---------------------------------------------------------------- K2a: rmsnorm -> z -> g -> u
// Columns-in-lanes: lane = active column; weight index wave-uniform -> s_load.
// grid: 16 col-groups(64) x 8 out-groups(32 u-rows): 128 blocks x 256.
__global__ __launch_bounds__(256) void k_core_a(
    const float* __restrict__ h, const float* __restrict__ xproj,
    const int* __restrict__ act_idx, const float* __restrict__ norm_w,
    const float* __restrict__ Wg, float* __restrict__ u_g)
{
    __shared__ float zt[128 * 64];        // [d][c] 32 KB
    __shared__ float ssq[4 * 64];
    __shared__ float rsb[64];
    int cg = blockIdx.x >> 3;             // 0..15
    int og = blockIdx.x & 7;              // 0..7
    int tid = threadIdx.x;
    int c = tid & 63;
    int seg = __builtin_amdgcn_readfirstlane(tid >> 6);   // wave id 0..3
    int b = cg >> 3;
    int sbase = (cg & 7) * 64;
    int n = act_idx[b * KK + sbase + c];
    float vals[32];
    float sq = 0.f;
    if (seg < 2) {
        const float* hp = h + ((size_t)(b * NN + n)) * DS + seg * 32;
#pragma unroll
        for (int i = 0; i < 32; i++) { float v = hp[i]; vals[i] = v; sq += v * v; }
    } else {
        const float* xp = xproj + b * DS + (seg - 2) * 32;
#pragma unroll
        for (int i = 0; i < 32; i++) { float v = xp[i]; vals[i] = v; sq += v * v; }
    }
    ssq[seg * 64 + c] = sq;
    __syncthreads();
    if (tid < 64) {
        float s = ssq[tid] + ssq[64 + tid] + ssq[128 + tid] + ssq[192 + tid];
        rsb[tid] = rsqrtf(s * (1.0f / DCAT) + 1e-6f);     // m-part zeros still count in mean
    }
    __syncthreads();
    {
        float rs = rsb[c];
#pragma unroll
        for (int i = 0; i < 32; i++) {
            int d = seg * 32 + i;
            zt[d * 64 + c] = norm_w[d] * vals[i] * rs;
        }
    }
    __syncthreads();
    float z[128];
#pragma unroll
    for (int d = 0; d < 128; d++) z[d] = zt[d * 64 + c];
    int rbase = og * 32 + seg * 8;
    float ga[8];
#pragma unroll
    for (int r = 0; r < 8; r++) {
        const float* wr = Wg + (rbase + r) * DCAT;        // uniform -> s_load
        float acc = 0.f;
#pragma unroll
        for (int d = 0; d < 128; d++) acc += z[d] * wr[d];
        ga[r] = acc;
    }
    int gcol = cg * 64 + c;
#pragma unroll
    for (int r = 0; r < 8; r++) {
        const float* wr = Wg + (256 + rbase + r) * DCAT;
        float bacc = 0.f;
#pragma unroll
        for (int d = 0; d < 128; d++) bacc += z[d] * wr[d];
        float uu = ga[r] * (bacc / (1.f + expf(-bacc)));  // a * silu(b)
        u_g[(rbase + r) * 1024 + gcol] = uu;              // coalesced [j][gcol]
    }
}

// ---------------------------------------------------------------- K2b: h_hat + h update + votes + qkv
// 32 blocks x 256; block = 32 active columns; split-K across 4 waves x 2 sub-halves.
__global__ __launch_bounds__(256) void k_core_b(
    float* __restrict__ h, const float* __restrict__ u_g,
    const int* __restrict__ act_idx, const float* __restrict__ Wout,
    const float* __restrict__ W_vote, const float* __restrict__ attn_in_w,
    float* __restrict__ qh, float* __restrict__ kh, float* __restrict__ vh)
{
    __shared__ float part[4 * 64 * 32];   // 32 KB
    __shared__ float hn[64 * 32];         // [d][c] 8 KB
    __shared__ float vv[64 * 32];         // [d][c] 8 KB
    __shared__ int an[32];
    int blk = blockIdx.x;
    int b = blk >> 4;
    int sbase = (blk & 15) * 32;
    int tid = threadIdx.x;
    int w = __builtin_amdgcn_readfirstlane(tid >> 6);
    int l = tid & 63;
    int c = l & 31, sub = l >> 5;
    if (tid < 32) an[tid] = act_idx[b * KK + sbase + tid];
    __syncthreads();
    // phase 1: partial h_hat over u chunk [w*64+sub*32, +32)
    float uu[32];
    int jb = w * 64 + sub * 32;
#pragma unroll
    for (int i = 0; i < 32; i++) uu[i] = u_g[(jb + i) * 1024 + b * KK + sbase + c];
#pragma unroll 8
    for (int o = 0; o < 64; o++) {
        const float* wr = Wout + o * 256 + jb;            // uniform
        float a = 0.f;
#pragma unroll
        for (int i = 0; i < 32; i++) a += uu[i] * wr[i];
        a += __shfl_xor(a, 32);
        if (sub == 0) part[(w * 64 + o) * 32 + c] = a;
    }
    __syncthreads();
    // phase 2: reduce 4 waves + h update
    {
        int cc = tid & 31, o0 = tid >> 5;
#pragma unroll
        for (int k = 0; k < 8; k++) {
            int o = o0 + k * 8;
            float s = part[o * 32 + cc] + part[(64 + o) * 32 + cc]
                    + part[(128 + o) * 32 + cc] + part[(192 + o) * 32 + cc];
            size_t hidx = ((size_t)(b * NN + an[cc])) * DS + o;
            float nh = h[hidx] + s;
            h[hidx] = nh;
            hn[o * 32 + cc] = nh;
        }
    }
    __syncthreads();
    // phase 3: votes v = W_vote @ h_new
    float hh[32];
#pragma unroll
    for (int i = 0; i < 32; i++) hh[i] = hn[(sub * 32 + i) * 32 + c];
#pragma unroll 4
    for (int oi = 0; oi < 16; oi++) {
        int o = w * 16 + oi;
        const float* wr = W_vote + o * 64 + sub * 32;     // uniform
        float a = 0.f;
#pragma unroll
        for (int i = 0; i < 32; i++) a += hh[i] * wr[i];
        a += __shfl_xor(a, 32);
        if (sub == 0) vv[o * 32 + c] = a;
    }
    __syncthreads();
    // qkv = attn_in_w @ v
    float vq[32];
#pragma unroll
    for (int i = 0; i < 32; i++) vq[i] = vv[(sub * 32 + i) * 32 + c];
    int slot = sbase + c;
#pragma unroll 4
    for (int oi = 0; oi < 48; oi++) {
        int r = w * 48 + oi;
        const float* wr = attn_in_w + r * 64 + sub * 32;  // uniform
        float a = 0.f;
#pragma unroll
        for (int i = 0; i < 32; i++) a += vq[i] * wr[i];
        a += __shfl_xor(a, 32);
        if (sub == 0) {
            if (r < 64) {
                qh[((b * HH + (r >> 4)) * KK + slot) * HD + (r & 15)] = a;
            } else if (r < 128) {
                int rr = r - 64;
                kh[((b * HH + (rr >> 4)) * HD + (rr & 15)) * KK + slot] = a;  // [hd][slot]
            } else {
                int rr = r - 128;
                vh[((b * HH + (rr >> 4)) * HD + (rr & 15)) * KK + slot] = a;  // [hd][slot]
            }
        }
    }
}

// ---------------------------------------------------------------- K3: attention for active queries
// wave per (bh, qs); K/V in [hd][slot] layout -> coalesced.
__global__ __launch_bounds__(256) void k_attn(
    const float* __restrict__ qh, const float* __restrict__ kh,
    const float* __restrict__ vh, float* __restrict__ m_raw)
{
    int wave = threadIdx.x >> 6, lane = threadIdx.x & 63;
    int task = blockIdx.x * 4 + wave;
    int qs = task & (KK - 1);
    int bh = task >> 9;
    const float* qp = qh + (bh * KK + qs) * HD;
    float q[HD];
#pragma unroll
    for (int d = 0; d < HD; d++) q[d] = qp[d];
    const float* kp = kh + bh * HD * KK;
    const float* vp = vh + bh * HD * KK;
    float lg[8]; float mx = -1e30f;
#pragma unroll
    for (int i = 0; i < 8; i++) {
        int slot = i * 64 + lane;
        float a = 0.f;
#pragma unroll
        for (int d = 0; d < HD; d++) a += q[d] * kp[d * KK + slot];
        lg[i] = a * 0.25f;
        mx = fmaxf(mx, lg[i]);
    }
    mx = wave_max(mx);
    float p[8]; float sum = 0.f;
#pragma unroll
    for (int i = 0; i < 8; i++) { p[i] = expf(lg[i] - mx); sum += p[i]; }
    sum = wave_sum(sum);
    float inv = 1.0f / sum;
    float acc[HD];
#pragma unroll
    for (int d = 0; d < HD; d++) acc[d] = 0.f;
#pragma unroll
    for (int i = 0; i < 8; i++) {
        int slot = i * 64 + lane;
        float pi = p[i];
#pragma unroll
        for (int d = 0; d < HD; d++) acc[d] += pi * vp[d * KK + slot];
    }
#pragma unroll
    for (int d = 0; d < HD; d++) acc[d] = wave_sum(acc[d]) * inv;
    if (lane == 0) {
        int b = bh >> 2, head = bh & 3;
#pragma unroll
        for (int d = 0; d < HD; d++)
            m_raw[(b * DV + head * HD + d) * KK + qs] = acc[d];   // [b][dv][slot]
    }
}

// ---------------------------------------------------------------- K4: FiLM (active) + mean-FiLM vectors
// blocks 0..15: active columns (64 each). blocks 16..17: mean message for batch b.
__global__ __launch_bounds__(256) void k_film(
    float* __restrict__ h, const int* __restrict__ act_idx,
    const float* __restrict__ m_raw, const float* __restrict__ vh,
    const float* __restrict__ attn_out_w, const float* __restrict__ Wfs,
    const float* __restrict__ Wfsh, float* __restrict__ fsm, float* __restrict__ fshm)
{
    __shared__ float mot[64 * 64];        // 16 KB (active branch)
    __shared__ int an[64];
    __shared__ float partm[4 * 64];
    __shared__ float mr[64];
    __shared__ float mo2[64];
    int blk = blockIdx.x;
    int tid = threadIdx.x;
    int lane = tid & 63;
    int w = __builtin_amdgcn_readfirstlane(tid >> 6);
    if (blk >= 16) {
        // mean over active slots of vh (uniform attention for inactive queries)
        int b = blk - 16;
        float macc[64];
#pragma unroll
        for (int d = 0; d < 64; d++) macc[d] = 0.f;
        for (int s = tid; s < KK; s += 256) {
#pragma unroll
            for (int d = 0; d < 64; d++) macc[d] += vh[(b * DV + d) * KK + s];
        }
#pragma unroll
        for (int d = 0; d < 64; d++) macc[d] = wave_sum(macc[d]);
        if (lane == 0) {
#pragma unroll
            for (int d = 0; d < 64; d++) partm[w * 64 + d] = macc[d];
        }
        __syncthreads();
        if (tid < 64)
            mr[tid] = (partm[tid] + partm[64 + tid] + partm[128 + tid] + partm[192 + tid]) * (1.0f / KK);
        __syncthreads();
        if (tid < 64) {
            const float* wo = attn_out_w + tid * DV;
            float a = 0.f;
#pragma unroll
            for (int e = 0; e < 64; e++) a += mr[e] * wo[e];
            mo2[tid] = a;
        }
        __syncthreads();
        if (tid < 64) {
            const float* ws = Wfs + tid * DV;
            const float* wh = Wfsh + tid * DV;
            float sc = 0.f, sh = 0.f;
#pragma unroll
            for (int e = 0; e < 64; e++) { float z = mo2[e]; sc += ws[e] * z; sh += wh[e] * z; }
            fsm[b * DS + tid] = tanhf(sc);
            fshm[b * DS + tid] = sh;
        }
        return;
    }
    // active-column FiLM: lane = slot-column
    int b = blk >> 3;
    int sbase = (blk & 7) * 64;
    if (tid < 64) an[tid] = act_idx[b * KK + sbase + tid];
    float md[64];
#pragma unroll
    for (int d = 0; d < 64; d++) md[d] = m_raw[(b * DV + d) * KK + sbase + lane];  // coalesced
#pragma unroll 4
    for (int oi = 0; oi < 16; oi++) {
        int o = w * 16 + oi;
        const float* wr = attn_out_w + o * 64;            // uniform
        float a = 0.f;
#pragma unroll
        for (int d = 0; d < 64; d++) a += md[d] * wr[d];
        mot[o * 64 + lane] = a;
    }
    __syncthreads();
    float mo[64];
#pragma unroll
    for (int e = 0; e < 64; e++) mo[e] = mot[e * 64 + lane];
#pragma unroll 4
    for (int oi = 0; oi < 16; oi++) {
        int o = w * 16 + oi;
        const float* ws = Wfs + o * 64;                   // uniform
        const float* wh = Wfsh + o * 64;
        float sc = 0.f, sh = 0.f;
#pragma unroll
        for (int e = 0; e < 64; e++) { sc += ws[e] * mo[e]; sh += wh[e] * mo[e]; }
        size_t idx = ((size_t)(b * NN + an[lane])) * DS + o;
        h[idx] = h[idx] * (1.f + tanhf(sc)) + sh;
    }
}

// ---------------------------------------------------------------- K5: inactive FiLM + pool + out + next gate
__global__ __launch_bounds__(1024) void k_pool(
    float* __restrict__ h, const int* __restrict__ col2slot,
    const float* __restrict__ fsm, const float* __restrict__ fshm,
    const float* __restrict__ query, const float* __restrict__ onw,
    const float* __restrict__ W_gate, const float* __restrict__ W_out,
    float* __restrict__ gate, float* __restrict__ out, int t)
{
    int b = blockIdx.x, tid = threadIdx.x;
    __shared__ float pl[NN];
    __shared__ float red[1024];
    __shared__ float part[16 * 64];
    __shared__ float pooled[64];
    __shared__ float qv[64], wg[64], fs[64], fh[64];
    if (tid < 64) {
        qv[tid] = query[tid]; wg[tid] = W_gate[tid];
        fs[tid] = fsm[b * DS + tid]; fh[tid] = fshm[b * DS + tid];
    }
    __syncthreads();
    float* hb = h + (size_t)b * NN * DS;
    for (int n = tid; n < NN; n += 1024) {
        float hv[64];
        float4* hp = (float4*)(hb + n * DS);
        int slot = col2slot[b * NN + n];
#pragma unroll
        for (int i = 0; i < 16; i++) {
            float4 v = hp[i];
            hv[i * 4] = v.x; hv[i * 4 + 1] = v.y; hv[i * 4 + 2] = v.z; hv[i * 4 + 3] = v.w;
        }
        if (slot < 0) {                   // inactive-column FiLM with mean message
#pragma unroll
            for (int d = 0; d < 64; d++) hv[d] = hv[d] * (1.f + fs[d]) + fh[d];
#pragma unroll
            for (int i = 0; i < 16; i++) {
                float4 v;
                v.x = hv[i * 4]; v.y = hv[i * 4 + 1]; v.z = hv[i * 4 + 2]; v.w = hv[i * 4 + 3];
                hp[i] = v;
            }
        }
        float lg = 0.f, gt = 0.f;
#pragma unroll
        for (int d = 0; d < 64; d++) { lg += qv[d] * hv[d]; gt += wg[d] * hv[d]; }
        pl[n] = lg * 0.125f;              // /sqrt(64)
        gate[b * NN + n] = gt;            // next step's gate
    }
    __syncthreads();
    red[tid] = fmaxf(pl[tid], pl[tid + 1024]);
    __syncthreads();
    for (int s = 512; s > 0; s >>= 1) { if (tid < s) red[tid] = fmaxf(red[tid], red[tid + s]); __syncthreads(); }
    float mx = red[0];
    __syncthreads();
    float e0 = expf(pl[tid] - mx), e1 = expf(pl[tid + 1024] - mx);
    pl[tid] = e0; pl[tid + 1024] = e1;
    red[tid] = e0 + e1;
    __syncthreads();
    for (int s = 512; s > 0; s >>= 1) { if (tid < s) red[tid] += red[tid + s]; __syncthreads(); }
    float inv = 1.0f / red[0];
    __syncthreads();
    int d = tid & 63, seg = tid >> 6;
    float acc = 0.f;
    for (int n = seg * 128; n < seg * 128 + 128; n++) acc += pl[n] * hb[n * DS + d];
    part[seg * 64 + d] = acc;
    __syncthreads();
    if (tid < 64) {
        float s = 0.f;
#pragma unroll
        for (int g = 0; g < 16; g++) s += part[g * 64 + tid];
        float v = s * inv;
        float ssv = wave_sum(v * v);
        float rs = rsqrtf(ssv * (1.0f / DS) + 1e-6f);
        pooled[tid] = onw[tid] * v * rs;
    }
    __syncthreads();
    if (tid < DI) {
        const float* wr = W_out + tid * DS;
        float acc2 = 0.f;
#pragma unroll
        for (int dd = 0; dd < DS; dd++) acc2 += pooled[dd] * wr[dd];
        out[(b * TT + t) * DI + tid] = acc2;
    }
}

// ----------------------------------------------------------------
extern "C" void kernel_launch(void* const* d_in, const int* in_sizes, int n_in,
                              void* d_out, int out_size, void* d_ws, size_t ws_size,
                              hipStream_t stream)
{
    const float* x          = (const float*)d_in[0];
    const float* W_in       = (const float*)d_in[1];
    const float* core_norm_w= (const float*)d_in[2];
    const float* core_Wg    = (const float*)d_in[3];
    const float* core_Wout  = (const float*)d_in[4];
    const float* W_gate     = (const float*)d_in[5];
    const float* W_vote     = (const float*)d_in[6];
    const float* attn_in_w  = (const float*)d_in[7];
    const float* attn_out_w = (const float*)d_in[8];
    const float* Wfs        = (const float*)d_in[9];
    const float* Wfsh       = (const float*)d_in[10];
    const float* query      = (const float*)d_in[11];
    const float* onw        = (const float*)d_in[12];
    const float* W_out      = (const float*)d_in[13];
    float* out = (float*)d_out;

    float* ws = (float*)d_ws;
    float* h        = ws;                              // 262144
    float* gate     = h + (size_t)BB * NN * DS;        // 4096
    float* xproj    = gate + BB * NN;                  // 128
    int*   col2slot = (int*)(xproj + BB * DS);         // 4096
    int*   act_idx  = col2slot + BB * NN;              // 1024
    float* u_g      = (float*)(act_idx + BB * KK);     // 262144
    float* qh       = u_g + 256 * 1024;                // 65536
    float* kh       = qh + BB * HH * KK * HD;
    float* vh       = kh + BB * HH * KK * HD;
    float* m_raw    = vh + BB * HH * KK * HD;          // 65536
    float* fsm      = m_raw + BB * DV * KK;            // 128
    float* fshm     = fsm + BB * DS;                   // 128

    // zero h and gate (adjacent) in one memset
    hipMemsetAsync(h, 0, ((size_t)BB * NN * DS + BB * NN) * sizeof(float), stream);

    for (int t = 0; t < TT; t++) {
        k_topk<<<BB, 1024, 0, stream>>>(gate, x, W_in, col2slot, act_idx, xproj, t);
        k_core_a<<<128, 256, 0, stream>>>(h, xproj, act_idx, core_norm_w, core_Wg, u_g);
        k_core_b<<<32, 256, 0, stream>>>(h, u_g, act_idx, core_Wout, W_vote, attn_in_w, qh, kh, vh);
        k_attn<<<BB * HH * KK / 4, 256, 0, stream>>>(qh, kh, vh, m_raw);
        k_film<<<18, 256, 0, stream>>>(h, act_idx, m_raw, vh, attn_out_w, Wfs, Wfsh, fsm, fshm);
        k_pool<<<BB, 1024, 0, stream>>>(h, col2slot, fsm, fshm, query, onw, W_gate, W_out, gate, out, t);
    }
}

// Round 3
// 530.523 us; speedup vs baseline: 1.7271x; 1.7271x over previous
//
#include <hip/hip_runtime.h>
#include <hip/hip_bf16.h>

// Model dims
#define NN 2048
#define DS 64
#define DI 256
#define DV 64
#define KK 512
#define HH 4
#define HD 16
#define BB 2
#define TT 4
#define DCAT 192

typedef unsigned long long ull;

__device__ __forceinline__ float wave_sum(float v) {
#pragma unroll
    for (int o = 32; o > 0; o >>= 1) v += __shfl_xor(v, o);
    return v;
}
__device__ __forceinline__ float wave_max(float v) {
#pragma unroll
    for (int o = 32; o > 0; o >>= 1) v = fmaxf(v, __shfl_xor(v, o));
    return v;
}
__device__ __forceinline__ unsigned enc_f(float f) {
    unsigned u = __float_as_uint(f);
    return (u & 0x80000000u) ? ~u : (u | 0x80000000u);
}
__device__ __forceinline__ float dec_f(unsigned u) {
    unsigned bits = (u & 0x80000000u) ? (u & 0x7FFFFFFFu) : ~u;
    return __uint_as_float(bits);
}

// ---------------------------------------------------------------- K1: radix-select top-k + xproj
// Exact top-K set of (gate, lowest-index-tiebreak) via u64 key radix select.
// Slot order is arbitrary (all downstream consumers are permutation-invariant).
__global__ __launch_bounds__(1024) void k_topk(
    const float* __restrict__ gate, const float* __restrict__ x,
    const float* __restrict__ W_in, int* __restrict__ col2slot,
    int* __restrict__ act_idx, float* __restrict__ xproj,
    unsigned* __restrict__ plmax, int t)
{
    int b = blockIdx.x, tid = threadIdx.x;
    __shared__ ull keys[NN];              // 16 KB
    __shared__ unsigned hist[256];
    __shared__ unsigned suf[256];
    __shared__ ull pref_sh;
    __shared__ int need_sh;
    __shared__ unsigned cnt;
    if (tid < DS) {                       // xproj: x_t @ W_in.T
        const float* xp = x + (b * TT + t) * DI;
        const float* wr = W_in + tid * DI;
        float acc = 0.f;
#pragma unroll 4
        for (int i = 0; i < DI; i++) acc += xp[i] * wr[i];
        xproj[b * DS + tid] = acc;
    }
    if (tid == 0) { cnt = 0; plmax[b] = 0; }
    for (int i = tid; i < NN; i += 1024) {
        keys[i] = ((ull)enc_f(gate[b * NN + i]) << 32) | (unsigned)(NN - 1 - i);
        col2slot[b * NN + i] = -1;
    }
    ull prefix = 0, pmask = 0;
    int need = KK;
    for (int shift = 56; shift >= 0; shift -= 8) {
        if (tid < 256) hist[tid] = 0;
        __syncthreads();
        for (int i = tid; i < NN; i += 1024) {
            ull k = keys[i];
            if ((k & pmask) == prefix)
                atomicAdd(&hist[(unsigned)((k >> shift) & 255)], 1u);
        }
        __syncthreads();
        if (tid < 256) suf[tid] = hist[tid];
        __syncthreads();
        for (int s = 1; s < 256; s <<= 1) {        // suffix sum: suf[d] = #digit >= d
            unsigned v = 0;
            if (tid < 256 && tid + s < 256) v = suf[tid + s];
            __syncthreads();
            if (tid < 256) suf[tid] += v;
            __syncthreads();
        }
        if (tid < 256) {
            unsigned here = suf[tid];
            unsigned above = (tid == 255) ? 0u : suf[tid + 1];
            if (here >= (unsigned)need && above < (unsigned)need) {
                pref_sh = prefix | ((ull)tid << shift);
                need_sh = need - (int)above;
            }
        }
        __syncthreads();
        prefix = pref_sh;
        need = need_sh;
        pmask |= (0xFFull << shift);
        __syncthreads();
    }
    // prefix == exact K-th largest key; distinct keys -> exactly K with key >= prefix
    for (int i = tid; i < NN; i += 1024) {
        ull k = keys[i];
        if (k >= prefix) {
            unsigned p = atomicAdd(&cnt, 1u);
            int n = NN - 1 - (int)(k & 0xFFFFFFFFull);
            act_idx[b * KK + p] = n;
            col2slot[b * NN + n] = (int)p;
        }
    }
}

// ---------------------------------------------------------------- K2a: rmsnorm -> z -> g -> u
__global__ __launch_bounds__(256) void k_core_a(
    const float* __restrict__ h, const float* __restrict__ xproj,
    const int* __restrict__ act_idx, const float* __restrict__ norm_w,
    const float* __restrict__ Wg, float* __restrict__ u_g)
{
    __shared__ float zt[128 * 64];        // [d][c] 32 KB
    __shared__ float ssq[4 * 64];
    __shared__ float rsb[64];
    int cg = blockIdx.x >> 3;             // 0..15
    int og = blockIdx.x & 7;              // 0..7
    int tid = threadIdx.x;
    int c = tid & 63;
    int seg = __builtin_amdgcn_readfirstlane(tid >> 6);
    int b = cg >> 3;
    int sbase = (cg & 7) * 64;
    int n = act_idx[b * KK + sbase + c];
    float vals[32];
    float sq = 0.f;
    if (seg < 2) {
        const float* hp = h + ((size_t)(b * NN + n)) * DS + seg * 32;
#pragma unroll
        for (int i = 0; i < 32; i++) { float v = hp[i]; vals[i] = v; sq += v * v; }
    } else {
        const float* xp = xproj + b * DS + (seg - 2) * 32;
#pragma unroll
        for (int i = 0; i < 32; i++) { float v = xp[i]; vals[i] = v; sq += v * v; }
    }
    ssq[seg * 64 + c] = sq;
    __syncthreads();
    if (tid < 64) {
        float s = ssq[tid] + ssq[64 + tid] + ssq[128 + tid] + ssq[192 + tid];
        rsb[tid] = rsqrtf(s * (1.0f / DCAT) + 1e-6f);
    }
    __syncthreads();
    {
        float rs = rsb[c];
#pragma unroll
        for (int i = 0; i < 32; i++) {
            int d = seg * 32 + i;
            zt[d * 64 + c] = norm_w[d] * vals[i] * rs;
        }
    }
    __syncthreads();
    float z[128];
#pragma unroll
    for (int d = 0; d < 128; d++) z[d] = zt[d * 64 + c];
    int rbase = og * 32 + seg * 8;
    float ga[8];
#pragma unroll
    for (int r = 0; r < 8; r++) {
        const float* wr = Wg + (rbase + r) * DCAT;
        float acc = 0.f;
#pragma unroll
        for (int d = 0; d < 128; d++) acc += z[d] * wr[d];
        ga[r] = acc;
    }
    int gcol = cg * 64 + c;
#pragma unroll
    for (int r = 0; r < 8; r++) {
        const float* wr = Wg + (256 + rbase + r) * DCAT;
        float bacc = 0.f;
#pragma unroll
        for (int d = 0; d < 128; d++) bacc += z[d] * wr[d];
        float uu = ga[r] * (bacc / (1.f + expf(-bacc)));
        u_g[(rbase + r) * 1024 + gcol] = uu;
    }
}

// ---------------------------------------------------------------- K2b: h_hat + h update + votes + qkv
__global__ __launch_bounds__(256) void k_core_b(
    float* __restrict__ h, const float* __restrict__ u_g,
    const int* __restrict__ act_idx, const float* __restrict__ Wout,
    const float* __restrict__ W_vote, const float* __restrict__ attn_in_w,
    float* __restrict__ qh, float* __restrict__ kh, float* __restrict__ vh)
{
    __shared__ float part[4 * 64 * 32];
    __shared__ float hn[64 * 32];
    __shared__ float vv[64 * 32];
    __shared__ int an[32];
    int blk = blockIdx.x;
    int b = blk >> 4;
    int sbase = (blk & 15) * 32;
    int tid = threadIdx.x;
    int w = __builtin_amdgcn_readfirstlane(tid >> 6);
    int l = tid & 63;
    int c = l & 31, sub = l >> 5;
    if (tid < 32) an[tid] = act_idx[b * KK + sbase + tid];
    __syncthreads();
    float uu[32];
    int jb = w * 64 + sub * 32;
#pragma unroll
    for (int i = 0; i < 32; i++) uu[i] = u_g[(jb + i) * 1024 + b * KK + sbase + c];
#pragma unroll 8
    for (int o = 0; o < 64; o++) {
        const float* wr = Wout + o * 256 + jb;
        float a = 0.f;
#pragma unroll
        for (int i = 0; i < 32; i++) a += uu[i] * wr[i];
        a += __shfl_xor(a, 32);
        if (sub == 0) part[(w * 64 + o) * 32 + c] = a;
    }
    __syncthreads();
    {
        int cc = tid & 31, o0 = tid >> 5;
#pragma unroll
        for (int k = 0; k < 8; k++) {
            int o = o0 + k * 8;
            float s = part[o * 32 + cc] + part[(64 + o) * 32 + cc]
                    + part[(128 + o) * 32 + cc] + part[(192 + o) * 32 + cc];
            size_t hidx = ((size_t)(b * NN + an[cc])) * DS + o;
            float nh = h[hidx] + s;
            h[hidx] = nh;
            hn[o * 32 + cc] = nh;
        }
    }
    __syncthreads();
    float hh[32];
#pragma unroll
    for (int i = 0; i < 32; i++) hh[i] = hn[(sub * 32 + i) * 32 + c];
#pragma unroll 4
    for (int oi = 0; oi < 16; oi++) {
        int o = w * 16 + oi;
        const float* wr = W_vote + o * 64 + sub * 32;
        float a = 0.f;
#pragma unroll
        for (int i = 0; i < 32; i++) a += hh[i] * wr[i];
        a += __shfl_xor(a, 32);
        if (sub == 0) vv[o * 32 + c] = a;
    }
    __syncthreads();
    float vq[32];
#pragma unroll
    for (int i = 0; i < 32; i++) vq[i] = vv[(sub * 32 + i) * 32 + c];
    int slot = sbase + c;
#pragma unroll 4
    for (int oi = 0; oi < 48; oi++) {
        int r = w * 48 + oi;
        const float* wr = attn_in_w + r * 64 + sub * 32;
        float a = 0.f;
#pragma unroll
        for (int i = 0; i < 32; i++) a += vq[i] * wr[i];
        a += __shfl_xor(a, 32);
        if (sub == 0) {
            if (r < 64) {
                qh[((b * HH + (r >> 4)) * KK + slot) * HD + (r & 15)] = a;
            } else if (r < 128) {
                int rr = r - 64;
                kh[((b * HH + (rr >> 4)) * HD + (rr & 15)) * KK + slot] = a;
            } else {
                int rr = r - 128;
                vh[((b * HH + (rr >> 4)) * HD + (rr & 15)) * KK + slot] = a;
            }
        }
    }
}

// ---------------------------------------------------------------- K3: attention for active queries
__global__ __launch_bounds__(256) void k_attn(
    const float* __restrict__ qh, const float* __restrict__ kh,
    const float* __restrict__ vh, float* __restrict__ m_raw)
{
    int wave = threadIdx.x >> 6, lane = threadIdx.x & 63;
    int task = blockIdx.x * 4 + wave;
    int qs = task & (KK - 1);
    int bh = task >> 9;
    const float* qp = qh + (bh * KK + qs) * HD;
    float q[HD];
#pragma unroll
    for (int d = 0; d < HD; d++) q[d] = qp[d];
    const float* kp = kh + bh * HD * KK;
    const float* vp = vh + bh * HD * KK;
    float lg[8]; float mx = -1e30f;
#pragma unroll
    for (int i = 0; i < 8; i++) {
        int slot = i * 64 + lane;
        float a = 0.f;
#pragma unroll
        for (int d = 0; d < HD; d++) a += q[d] * kp[d * KK + slot];
        lg[i] = a * 0.25f;
        mx = fmaxf(mx, lg[i]);
    }
    mx = wave_max(mx);
    float p[8]; float sum = 0.f;
#pragma unroll
    for (int i = 0; i < 8; i++) { p[i] = expf(lg[i] - mx); sum += p[i]; }
    sum = wave_sum(sum);
    float inv = 1.0f / sum;
    float acc[HD];
#pragma unroll
    for (int d = 0; d < HD; d++) acc[d] = 0.f;
#pragma unroll
    for (int i = 0; i < 8; i++) {
        int slot = i * 64 + lane;
        float pi = p[i];
#pragma unroll
        for (int d = 0; d < HD; d++) acc[d] += pi * vp[d * KK + slot];
    }
#pragma unroll
    for (int d = 0; d < HD; d++) acc[d] = wave_sum(acc[d]) * inv;
    if (lane == 0) {
        int b = bh >> 2, head = bh & 3;
#pragma unroll
        for (int d = 0; d < HD; d++)
            m_raw[(b * DV + head * HD + d) * KK + qs] = acc[d];
    }
}

// ---------------------------------------------------------------- K4: FiLM (active) + mean-FiLM vectors
__global__ __launch_bounds__(256) void k_film(
    float* __restrict__ h, const int* __restrict__ act_idx,
    const float* __restrict__ m_raw, const float* __restrict__ vh,
    const float* __restrict__ attn_out_w, const float* __restrict__ Wfs,
    const float* __restrict__ Wfsh, float* __restrict__ fsm, float* __restrict__ fshm)
{
    __shared__ float mot[64 * 64];
    __shared__ int an[64];
    __shared__ float partm[4 * 64];
    __shared__ float mr[64];
    __shared__ float mo2[64];
    int blk = blockIdx.x;
    int tid = threadIdx.x;
    int lane = tid & 63;
    int w = __builtin_amdgcn_readfirstlane(tid >> 6);
    if (blk >= 16) {
        int b = blk - 16;
        float macc[64];
#pragma unroll
        for (int d = 0; d < 64; d++) macc[d] = 0.f;
        for (int s = tid; s < KK; s += 256) {
#pragma unroll
            for (int d = 0; d < 64; d++) macc[d] += vh[(b * DV + d) * KK + s];
        }
#pragma unroll
        for (int d = 0; d < 64; d++) macc[d] = wave_sum(macc[d]);
        if (lane == 0) {
#pragma unroll
            for (int d = 0; d < 64; d++) partm[w * 64 + d] = macc[d];
        }
        __syncthreads();
        if (tid < 64)
            mr[tid] = (partm[tid] + partm[64 + tid] + partm[128 + tid] + partm[192 + tid]) * (1.0f / KK);
        __syncthreads();
        if (tid < 64) {
            const float* wo = attn_out_w + tid * DV;
            float a = 0.f;
#pragma unroll
            for (int e = 0; e < 64; e++) a += mr[e] * wo[e];
            mo2[tid] = a;
        }
        __syncthreads();
        if (tid < 64) {
            const float* ws = Wfs + tid * DV;
            const float* wh = Wfsh + tid * DV;
            float sc = 0.f, sh = 0.f;
#pragma unroll
            for (int e = 0; e < 64; e++) { float z = mo2[e]; sc += ws[e] * z; sh += wh[e] * z; }
            fsm[b * DS + tid] = tanhf(sc);
            fshm[b * DS + tid] = sh;
        }
        return;
    }
    int b = blk >> 3;
    int sbase = (blk & 7) * 64;
    if (tid < 64) an[tid] = act_idx[b * KK + sbase + tid];
    float md[64];
#pragma unroll
    for (int d = 0; d < 64; d++) md[d] = m_raw[(b * DV + d) * KK + sbase + lane];
#pragma unroll 4
    for (int oi = 0; oi < 16; oi++) {
        int o = w * 16 + oi;
        const float* wr = attn_out_w + o * 64;
        float a = 0.f;
#pragma unroll
        for (int d = 0; d < 64; d++) a += md[d] * wr[d];
        mot[o * 64 + lane] = a;
    }
    __syncthreads();
    float mo[64];
#pragma unroll
    for (int e = 0; e < 64; e++) mo[e] = mot[e * 64 + lane];
#pragma unroll 4
    for (int oi = 0; oi < 16; oi++) {
        int o = w * 16 + oi;
        const float* ws = Wfs + o * 64;
        const float* wh = Wfsh + o * 64;
        float sc = 0.f, sh = 0.f;
#pragma unroll
        for (int e = 0; e < 64; e++) { sc += ws[e] * mo[e]; sh += wh[e] * mo[e]; }
        size_t idx = ((size_t)(b * NN + an[lane])) * DS + o;
        h[idx] = h[idx] * (1.f + tanhf(sc)) + sh;
    }
}

// ---------------------------------------------------------------- K5a: inactive FiLM + logits + next gate + global max
// 128 blocks x 256: block = (b, 32-column group); wave handles 8 columns.
__global__ __launch_bounds__(256) void k_poolA(
    float* __restrict__ h, const int* __restrict__ col2slot,
    const float* __restrict__ fsm, const float* __restrict__ fshm,
    const float* __restrict__ query, const float* __restrict__ W_gate,
    float* __restrict__ gate, float* __restrict__ pl, unsigned* __restrict__ plmax)
{
    __shared__ unsigned lmax;
    int blk = blockIdx.x;
    int b = blk >> 6;
    int base = (blk & 63) * 32;
    int tid = threadIdx.x;
    int w = tid >> 6, lane = tid & 63;
    if (tid == 0) lmax = 0;
    float fs = fsm[b * DS + lane], fh = fshm[b * DS + lane];
    float qv = query[lane] * 0.125f, wg = W_gate[lane];
    __syncthreads();
    float wmax = -1e30f;
#pragma unroll
    for (int ci = 0; ci < 8; ci++) {
        int n = base + w * 8 + ci;
        size_t idx = ((size_t)(b * NN + n)) * DS + lane;
        float hv = h[idx];
        int slot = col2slot[b * NN + n];
        if (slot < 0) { hv = hv * (1.f + fs) + fh; h[idx] = hv; }
        float lg = wave_sum(qv * hv);
        float gt = wave_sum(wg * hv);
        if (lane == 0) { pl[b * NN + n] = lg; gate[b * NN + n] = gt; }
        wmax = fmaxf(wmax, lg);
    }
    if (lane == 0) atomicMax(&lmax, enc_f(wmax));
    __syncthreads();
    if (tid == 0) atomicMax(&plmax[b], lmax);
}

// ---------------------------------------------------------------- K5b: exp-weighted partial pooled sums
__global__ __launch_bounds__(256) void k_poolB(
    const float* __restrict__ h, const float* __restrict__ pl,
    const unsigned* __restrict__ plmax,
    float* __restrict__ ppool, float* __restrict__ psum)
{
    __shared__ float part[4 * 64];
    __shared__ float swp[4];
    int blk = blockIdx.x;
    int b = blk >> 6;
    int base = (blk & 63) * 32;
    int tid = threadIdx.x;
    int w = tid >> 6, lane = tid & 63;
    float mx = dec_f(plmax[b]);
    float pacc = 0.f, sw = 0.f;
#pragma unroll
    for (int ci = 0; ci < 8; ci++) {
        int n = base + w * 8 + ci;
        float hv = h[((size_t)(b * NN + n)) * DS + lane];
        float wgt = expf(pl[b * NN + n] - mx);
        pacc += wgt * hv;
        sw += wgt;
    }
    part[w * 64 + lane] = pacc;
    if (lane == 0) swp[w] = sw;
    __syncthreads();
    if (tid < 64) ppool[blk * 64 + tid] = part[tid] + part[64 + tid] + part[128 + tid] + part[192 + tid];
    if (tid == 64) psum[blk] = swp[0] + swp[1] + swp[2] + swp[3];
}

// ---------------------------------------------------------------- K5c: reduce + rmsnorm + W_out
__global__ __launch_bounds__(256) void k_out(
    const float* __restrict__ ppool, const float* __restrict__ psum,
    const float* __restrict__ onw, const float* __restrict__ W_out,
    float* __restrict__ out, int t)
{
    __shared__ float pn[2][64];
    int tid = threadIdx.x;
    if (tid < 128) {
        int b = tid >> 6, d = tid & 63;
        float s = 0.f;
#pragma unroll 8
        for (int i = 0; i < 64; i++) s += ppool[(b * 64 + i) * 64 + d];
        float se = 0.f;
#pragma unroll 8
        for (int i = 0; i < 64; i++) se += psum[b * 64 + i];
        float v = s / se;
        float ss = wave_sum(v * v);
        float rs = rsqrtf(ss * (1.0f / DS) + 1e-6f);
        pn[b][d] = onw[d] * v * rs;
    }
    __syncthreads();
    int b = tid >> 7, o0 = (tid & 127) * 2;
#pragma unroll
    for (int k = 0; k < 2; k++) {
        int o = o0 + k;
        const float* wr = W_out + o * DS;
        float a = 0.f;
#pragma unroll
        for (int d = 0; d < DS; d++) a += pn[b][d] * wr[d];
        out[(b * TT + t) * DI + o] = a;
    }
}

// ----------------------------------------------------------------
extern "C" void kernel_launch(void* const* d_in, const int* in_sizes, int n_in,
                              void* d_out, int out_size, void* d_ws, size_t ws_size,
                              hipStream_t stream)
{
    const float* x          = (const float*)d_in[0];
    const float* W_in       = (const float*)d_in[1];
    const float* core_norm_w= (const float*)d_in[2];
    const float* core_Wg    = (const float*)d_in[3];
    const float* core_Wout  = (const float*)d_in[4];
    const float* W_gate     = (const float*)d_in[5];
    const float* W_vote     = (const float*)d_in[6];
    const float* attn_in_w  = (const float*)d_in[7];
    const float* attn_out_w = (const float*)d_in[8];
    const float* Wfs        = (const float*)d_in[9];
    const float* Wfsh       = (const float*)d_in[10];
    const float* query      = (const float*)d_in[11];
    const float* onw        = (const float*)d_in[12];
    const float* W_out      = (const float*)d_in[13];
    float* out = (float*)d_out;

    float* ws = (float*)d_ws;
    float* h        = ws;                              // 262144
    float* gate     = h + (size_t)BB * NN * DS;        // 4096
    float* xproj    = gate + BB * NN;                  // 128
    int*   col2slot = (int*)(xproj + BB * DS);         // 4096
    int*   act_idx  = col2slot + BB * NN;              // 1024
    float* u_g      = (float*)(act_idx + BB * KK);     // 262144
    float* qh       = u_g + 256 * 1024;                // 65536
    float* kh       = qh + BB * HH * KK * HD;
    float* vh       = kh + BB * HH * KK * HD;
    float* m_raw    = vh + BB * HH * KK * HD;          // 65536
    float* fsm      = m_raw + BB * DV * KK;            // 128
    float* fshm     = fsm + BB * DS;                   // 128
    float* pl       = fshm + BB * DS;                  // 4096
    float* ppool    = pl + BB * NN;                    // 8192
    float* psum     = ppool + 128 * 64;                // 128
    unsigned* plmax = (unsigned*)(psum + 128);         // 2

    hipMemsetAsync(h, 0, ((size_t)BB * NN * DS + BB * NN) * sizeof(float), stream);

    for (int t = 0; t < TT; t++) {
        k_topk<<<BB, 1024, 0, stream>>>(gate, x, W_in, col2slot, act_idx, xproj, plmax, t);
        k_core_a<<<128, 256, 0, stream>>>(h, xproj, act_idx, core_norm_w, core_Wg, u_g);
        k_core_b<<<32, 256, 0, stream>>>(h, u_g, act_idx, core_Wout, W_vote, attn_in_w, qh, kh, vh);
        k_attn<<<BB * HH * KK / 4, 256, 0, stream>>>(qh, kh, vh, m_raw);
        k_film<<<18, 256, 0, stream>>>(h, act_idx, m_raw, vh, attn_out_w, Wfs, Wfsh, fsm, fshm);
        k_poolA<<<128, 256, 0, stream>>>(h, col2slot, fsm, fshm, query, W_gate, gate, pl, plmax);
        k_poolB<<<128, 256, 0, stream>>>(h, pl, plmax, ppool, psum);
        k_out<<<1, 256, 0, stream>>>(ppool, psum, onw, W_out, out, t);
    }
}

// Round 4
// 499.597 us; speedup vs baseline: 1.8340x; 1.0619x over previous
//
#include <hip/hip_runtime.h>
#include <hip/hip_bf16.h>

// Model dims
#define NN 2048
#define DS 64
#define DI 256
#define DV 64
#define KK 512
#define HH 4
#define HD 16
#define BB 2
#define TT 4
#define DCAT 192

typedef unsigned long long ull;

__device__ __forceinline__ float wave_sum(float v) {
#pragma unroll
    for (int o = 32; o > 0; o >>= 1) v += __shfl_xor(v, o);
    return v;
}
__device__ __forceinline__ float wave_max(float v) {
#pragma unroll
    for (int o = 32; o > 0; o >>= 1) v = fmaxf(v, __shfl_xor(v, o));
    return v;
}
__device__ __forceinline__ unsigned enc_f(float f) {
    unsigned u = __float_as_uint(f);
    return (u & 0x80000000u) ? ~u : (u | 0x80000000u);
}

// ---------------------------------------------------------------- K1: radix-select top-k + xproj
// t==0: h==0 -> gate==0 -> jax.lax.top_k (stable) returns indices 0..K-1. Fast path.
__global__ __launch_bounds__(1024) void k_topk(
    const float* __restrict__ gate, const float* __restrict__ x,
    const float* __restrict__ W_in, int* __restrict__ col2slot,
    int* __restrict__ act_idx, float* __restrict__ xproj, int t)
{
    int b = blockIdx.x, tid = threadIdx.x;
    __shared__ ull keys[NN];              // 16 KB
    __shared__ unsigned hist[256];
    __shared__ unsigned suf[256];
    __shared__ ull pref_sh;
    __shared__ int need_sh;
    __shared__ unsigned cnt;
    if (tid < DS) {                       // xproj: x_t @ W_in.T
        const float* xp = x + (b * TT + t) * DI;
        const float* wr = W_in + tid * DI;
        float acc = 0.f;
#pragma unroll 4
        for (int i = 0; i < DI; i++) acc += xp[i] * wr[i];
        xproj[b * DS + tid] = acc;
    }
    if (t == 0) {                         // exact-tie fast path
        for (int i = tid; i < NN; i += 1024) col2slot[b * NN + i] = (i < KK) ? i : -1;
        if (tid < KK) act_idx[b * KK + tid] = tid;
        return;
    }
    if (tid == 0) cnt = 0;
    for (int i = tid; i < NN; i += 1024) {
        keys[i] = ((ull)enc_f(gate[b * NN + i]) << 32) | (unsigned)(NN - 1 - i);
        col2slot[b * NN + i] = -1;
    }
    ull prefix = 0, pmask = 0;
    int need = KK;
    for (int shift = 56; shift >= 0; shift -= 8) {
        if (tid < 256) hist[tid] = 0;
        __syncthreads();
        for (int i = tid; i < NN; i += 1024) {
            ull k = keys[i];
            if ((k & pmask) == prefix)
                atomicAdd(&hist[(unsigned)((k >> shift) & 255)], 1u);
        }
        __syncthreads();
        if (tid < 256) suf[tid] = hist[tid];
        __syncthreads();
        for (int s = 1; s < 256; s <<= 1) {        // suffix sum
            unsigned v = 0;
            if (tid < 256 && tid + s < 256) v = suf[tid + s];
            __syncthreads();
            if (tid < 256) suf[tid] += v;
            __syncthreads();
        }
        if (tid < 256) {
            unsigned here = suf[tid];
            unsigned above = (tid == 255) ? 0u : suf[tid + 1];
            if (here >= (unsigned)need && above < (unsigned)need) {
                pref_sh = prefix | ((ull)tid << shift);
                need_sh = need - (int)above;
            }
        }
        __syncthreads();
        prefix = pref_sh;
        need = need_sh;
        pmask |= (0xFFull << shift);
        __syncthreads();
    }
    for (int i = tid; i < NN; i += 1024) {
        ull k = keys[i];
        if (k >= prefix) {
            unsigned p = atomicAdd(&cnt, 1u);
            int n = NN - 1 - (int)(k & 0xFFFFFFFFull);
            act_idx[b * KK + p] = n;
            col2slot[b * NN + n] = (int)p;
        }
    }
}

// ---------------------------------------------------------------- K2a: rmsnorm -> z -> g -> u
// 256 blocks = 16 col-groups x 16 out-groups (16 u-rows each).
__global__ __launch_bounds__(256) void k_core_a(
    const float* __restrict__ h, const float* __restrict__ xproj,
    const int* __restrict__ act_idx, const float* __restrict__ norm_w,
    const float* __restrict__ Wg, float* __restrict__ u_g)
{
    __shared__ float zt[128 * 64];        // [d][c] 32 KB
    __shared__ float ssq[4 * 64];
    __shared__ float rsb[64];
    int cg = blockIdx.x >> 4;             // 0..15
    int og = blockIdx.x & 15;             // 0..15
    int tid = threadIdx.x;
    int c = tid & 63;
    int seg = __builtin_amdgcn_readfirstlane(tid >> 6);
    int b = cg >> 3;
    int sbase = (cg & 7) * 64;
    int n = act_idx[b * KK + sbase + c];
    float vals[32];
    float sq = 0.f;
    if (seg < 2) {
        const float* hp = h + ((size_t)(b * NN + n)) * DS + seg * 32;
#pragma unroll
        for (int i = 0; i < 32; i++) { float v = hp[i]; vals[i] = v; sq += v * v; }
    } else {
        const float* xp = xproj + b * DS + (seg - 2) * 32;
#pragma unroll
        for (int i = 0; i < 32; i++) { float v = xp[i]; vals[i] = v; sq += v * v; }
    }
    ssq[seg * 64 + c] = sq;
    __syncthreads();
    if (tid < 64) {
        float s = ssq[tid] + ssq[64 + tid] + ssq[128 + tid] + ssq[192 + tid];
        rsb[tid] = rsqrtf(s * (1.0f / DCAT) + 1e-6f);
    }
    __syncthreads();
    {
        float rs = rsb[c];
#pragma unroll
        for (int i = 0; i < 32; i++) {
            int d = seg * 32 + i;
            zt[d * 64 + c] = norm_w[d] * vals[i] * rs;
        }
    }
    __syncthreads();
    float z[128];
#pragma unroll
    for (int d = 0; d < 128; d++) z[d] = zt[d * 64 + c];
    int rbase = og * 16 + seg * 4;
    float ga[4];
#pragma unroll
    for (int r = 0; r < 4; r++) {
        const float* wr = Wg + (rbase + r) * DCAT;        // uniform -> s_load
        float acc = 0.f;
#pragma unroll
        for (int d = 0; d < 128; d++) acc += z[d] * wr[d];
        ga[r] = acc;
    }
    int gcol = cg * 64 + c;
#pragma unroll
    for (int r = 0; r < 4; r++) {
        const float* wr = Wg + (256 + rbase + r) * DCAT;
        float bacc = 0.f;
#pragma unroll
        for (int d = 0; d < 128; d++) bacc += z[d] * wr[d];
        float uu = ga[r] * (bacc / (1.f + expf(-bacc)));  // a * silu(b)
        u_g[(rbase + r) * 1024 + gcol] = uu;              // [row][gcol] coalesced
    }
}

// ---------------------------------------------------------------- K2b: h_hat partials (split-K)
// 64 blocks = 16 col-groups x 4 K-chunks of 64 u-rows. All reads coalesced.
__global__ __launch_bounds__(256) void k_hupd(
    const float* __restrict__ u_g, const float* __restrict__ Wout,
    float* __restrict__ part)
{
    int blk = blockIdx.x;
    int cg = blk >> 2, kc = blk & 3;
    int tid = threadIdx.x;
    int c = tid & 63, w = tid >> 6;
    int gcol = cg * 64 + c;
    float uu[64];
#pragma unroll
    for (int i = 0; i < 64; i++) uu[i] = u_g[(kc * 64 + i) * 1024 + gcol];  // coalesced
#pragma unroll
    for (int oi = 0; oi < 16; oi++) {
        int o = w * 16 + oi;
        const float* wr = Wout + o * 256 + kc * 64;       // uniform -> s_load
        float acc = 0.f;
#pragma unroll
        for (int i = 0; i < 64; i++) acc += uu[i] * wr[i];
        part[(kc * 64 + o) * 1024 + gcol] = acc;          // coalesced
    }
}

// ---------------------------------------------------------------- K2c: h update + votes + qkv
__global__ __launch_bounds__(256) void k_vqkv(
    float* __restrict__ h, const float* __restrict__ part,
    const int* __restrict__ act_idx,
    const float* __restrict__ W_vote, const float* __restrict__ attn_in_w,
    float* __restrict__ qh, float* __restrict__ kh, float* __restrict__ vh)
{
    __shared__ float hn[64 * 32];         // [d][c]
    __shared__ float vv[64 * 32];         // [d][c]
    __shared__ int an[32];
    int blk = blockIdx.x;
    int b = blk >> 4;
    int sbase = (blk & 15) * 32;
    int tid = threadIdx.x;
    int w = __builtin_amdgcn_readfirstlane(tid >> 6);
    int l = tid & 63;
    int c = l & 31, sub = l >> 5;
    if (tid < 32) an[tid] = act_idx[b * KK + sbase + tid];
    __syncthreads();
    // phase 1: reduce 4 split-K partials + h update
    {
        int cc = tid & 31, o0 = tid >> 5;
        int gcol = b * KK + sbase + cc;
#pragma unroll
        for (int kk = 0; kk < 8; kk++) {
            int o = o0 + kk * 8;
            float s = part[o * 1024 + gcol] + part[(64 + o) * 1024 + gcol]
                    + part[(128 + o) * 1024 + gcol] + part[(192 + o) * 1024 + gcol];
            size_t hidx = ((size_t)(b * NN + an[cc])) * DS + o;
            float nh = h[hidx] + s;
            h[hidx] = nh;
            hn[o * 32 + cc] = nh;
        }
    }
    __syncthreads();
    // phase 2: votes v = W_vote @ h_new
    float hh[32];
#pragma unroll
    for (int i = 0; i < 32; i++) hh[i] = hn[(sub * 32 + i) * 32 + c];
#pragma unroll 4
    for (int oi = 0; oi < 16; oi++) {
        int o = w * 16 + oi;
        const float* wr = W_vote + o * 64 + sub * 32;     // uniform
        float a = 0.f;
#pragma unroll
        for (int i = 0; i < 32; i++) a += hh[i] * wr[i];
        a += __shfl_xor(a, 32);
        if (sub == 0) vv[o * 32 + c] = a;
    }
    __syncthreads();
    // phase 3: qkv = attn_in_w @ v
    float vq[32];
#pragma unroll
    for (int i = 0; i < 32; i++) vq[i] = vv[(sub * 32 + i) * 32 + c];
    int slot = sbase + c;
#pragma unroll 4
    for (int oi = 0; oi < 48; oi++) {
        int r = w * 48 + oi;
        const float* wr = attn_in_w + r * 64 + sub * 32;  // uniform
        float a = 0.f;
#pragma unroll
        for (int i = 0; i < 32; i++) a += vq[i] * wr[i];
        a += __shfl_xor(a, 32);
        if (sub == 0) {
            if (r < 64) {
                qh[((b * HH + (r >> 4)) * KK + slot) * HD + (r & 15)] = a;
            } else if (r < 128) {
                int rr = r - 64;
                kh[((b * HH + (rr >> 4)) * HD + (rr & 15)) * KK + slot] = a;  // [hd][slot]
            } else {
                int rr = r - 128;
                vh[((b * HH + (rr >> 4)) * HD + (rr & 15)) * KK + slot] = a;  // [hd][slot]
            }
        }
    }
}

// ---------------------------------------------------------------- K3: attention for active queries
__global__ __launch_bounds__(256) void k_attn(
    const float* __restrict__ qh, const float* __restrict__ kh,
    const float* __restrict__ vh, float* __restrict__ m_raw)
{
    int wave = threadIdx.x >> 6, lane = threadIdx.x & 63;
    int task = blockIdx.x * 4 + wave;
    int qs = task & (KK - 1);
    int bh = task >> 9;
    const float* qp = qh + (bh * KK + qs) * HD;
    float q[HD];
#pragma unroll
    for (int d = 0; d < HD; d++) q[d] = qp[d];
    const float* kp = kh + bh * HD * KK;
    const float* vp = vh + bh * HD * KK;
    float lg[8]; float mx = -1e30f;
#pragma unroll
    for (int i = 0; i < 8; i++) {
        int slot = i * 64 + lane;
        float a = 0.f;
#pragma unroll
        for (int d = 0; d < HD; d++) a += q[d] * kp[d * KK + slot];
        lg[i] = a * 0.25f;
        mx = fmaxf(mx, lg[i]);
    }
    mx = wave_max(mx);
    float p[8]; float sum = 0.f;
#pragma unroll
    for (int i = 0; i < 8; i++) { p[i] = expf(lg[i] - mx); sum += p[i]; }
    sum = wave_sum(sum);
    float inv = 1.0f / sum;
    float acc[HD];
#pragma unroll
    for (int d = 0; d < HD; d++) acc[d] = 0.f;
#pragma unroll
    for (int i = 0; i < 8; i++) {
        int slot = i * 64 + lane;
        float pi = p[i];
#pragma unroll
        for (int d = 0; d < HD; d++) acc[d] += pi * vp[d * KK + slot];
    }
#pragma unroll
    for (int d = 0; d < HD; d++) acc[d] = wave_sum(acc[d]) * inv;
    if (lane == 0) {
        int b = bh >> 2, head = bh & 3;
#pragma unroll
        for (int d = 0; d < HD; d++)
            m_raw[(b * DV + head * HD + d) * KK + qs] = acc[d];
    }
}

// ---------------------------------------------------------------- K4: FiLM (active) + mean-FiLM vectors
__global__ __launch_bounds__(256) void k_film(
    float* __restrict__ h, const int* __restrict__ act_idx,
    const float* __restrict__ m_raw, const float* __restrict__ vh,
    const float* __restrict__ attn_out_w, const float* __restrict__ Wfs,
    const float* __restrict__ Wfsh, float* __restrict__ fsm, float* __restrict__ fshm)
{
    __shared__ float mot[64 * 64];
    __shared__ int an[64];
    __shared__ float partm[4 * 64];
    __shared__ float mr[64];
    __shared__ float mo2[64];
    int blk = blockIdx.x;
    int tid = threadIdx.x;
    int lane = tid & 63;
    int w = __builtin_amdgcn_readfirstlane(tid >> 6);
    if (blk >= 16) {
        int b = blk - 16;
        float macc[64];
#pragma unroll
        for (int d = 0; d < 64; d++) macc[d] = 0.f;
        for (int s = tid; s < KK; s += 256) {
#pragma unroll
            for (int d = 0; d < 64; d++) macc[d] += vh[(b * DV + d) * KK + s];
        }
#pragma unroll
        for (int d = 0; d < 64; d++) macc[d] = wave_sum(macc[d]);
        if (lane == 0) {
#pragma unroll
            for (int d = 0; d < 64; d++) partm[w * 64 + d] = macc[d];
        }
        __syncthreads();
        if (tid < 64)
            mr[tid] = (partm[tid] + partm[64 + tid] + partm[128 + tid] + partm[192 + tid]) * (1.0f / KK);
        __syncthreads();
        if (tid < 64) {
            const float* wo = attn_out_w + tid * DV;
            float a = 0.f;
#pragma unroll
            for (int e = 0; e < 64; e++) a += mr[e] * wo[e];
            mo2[tid] = a;
        }
        __syncthreads();
        if (tid < 64) {
            const float* ws = Wfs + tid * DV;
            const float* wh = Wfsh + tid * DV;
            float sc = 0.f, sh = 0.f;
#pragma unroll
            for (int e = 0; e < 64; e++) { float z = mo2[e]; sc += ws[e] * z; sh += wh[e] * z; }
            fsm[b * DS + tid] = tanhf(sc);
            fshm[b * DS + tid] = sh;
        }
        return;
    }
    int b = blk >> 3;
    int sbase = (blk & 7) * 64;
    if (tid < 64) an[tid] = act_idx[b * KK + sbase + tid];
    float md[64];
#pragma unroll
    for (int d = 0; d < 64; d++) md[d] = m_raw[(b * DV + d) * KK + sbase + lane];
#pragma unroll 4
    for (int oi = 0; oi < 16; oi++) {
        int o = w * 16 + oi;
        const float* wr = attn_out_w + o * 64;
        float a = 0.f;
#pragma unroll
        for (int d = 0; d < 64; d++) a += md[d] * wr[d];
        mot[o * 64 + lane] = a;
    }
    __syncthreads();
    float mo[64];
#pragma unroll
    for (int e = 0; e < 64; e++) mo[e] = mot[e * 64 + lane];
#pragma unroll 4
    for (int oi = 0; oi < 16; oi++) {
        int o = w * 16 + oi;
        const float* ws = Wfs + o * 64;
        const float* wh = Wfsh + o * 64;
        float sc = 0.f, sh = 0.f;
#pragma unroll
        for (int e = 0; e < 64; e++) { sc += ws[e] * mo[e]; sh += wh[e] * mo[e]; }
        size_t idx = ((size_t)(b * NN + an[lane])) * DS + o;
        h[idx] = h[idx] * (1.f + tanhf(sc)) + sh;
    }
}

// ---------------------------------------------------------------- K5: inactive FiLM + gate + flash pool partials
__global__ __launch_bounds__(256) void k_pool2(
    float* __restrict__ h, const int* __restrict__ col2slot,
    const float* __restrict__ fsm, const float* __restrict__ fshm,
    const float* __restrict__ query, const float* __restrict__ W_gate,
    float* __restrict__ gate, float* __restrict__ ppool,
    float* __restrict__ psum, float* __restrict__ pmax)
{
    __shared__ float wvecs[4][64];
    __shared__ float wms[4], wss[4];
    int blk = blockIdx.x;
    int b = blk >> 6;
    int base = (blk & 63) * 32;
    int tid = threadIdx.x;
    int w = tid >> 6, lane = tid & 63;
    float fs = fsm[b * DS + lane], fh = fshm[b * DS + lane];
    float qv = query[lane] * 0.125f, wg = W_gate[lane];
    float wm = -1e30f, sw = 0.f, vec = 0.f;
#pragma unroll
    for (int ci = 0; ci < 8; ci++) {
        int n = base + w * 8 + ci;
        size_t idx = ((size_t)(b * NN + n)) * DS + lane;
        float hv = h[idx];
        int slot = col2slot[b * NN + n];
        if (slot < 0) { hv = hv * (1.f + fs) + fh; h[idx] = hv; }
        float lg = wave_sum(qv * hv);
        float gt = wave_sum(wg * hv);
        if (lane == 0) gate[b * NN + n] = gt;
        float nm = fmaxf(wm, lg);
        float scale = __expf(wm - nm);
        float e = __expf(lg - nm);
        sw = sw * scale + e;
        vec = vec * scale + e * hv;
        wm = nm;
    }
    wvecs[w][lane] = vec;
    if (lane == 0) { wms[w] = wm; wss[w] = sw; }
    __syncthreads();
    if (tid < 64) {
        float m4 = fmaxf(fmaxf(wms[0], wms[1]), fmaxf(wms[2], wms[3]));
        float s = 0.f, v = 0.f;
#pragma unroll
        for (int ww = 0; ww < 4; ww++) {
            float e = __expf(wms[ww] - m4);
            s += wss[ww] * e;
            v += wvecs[ww][tid] * e;
        }
        ppool[blk * 64 + tid] = v;
        if (tid == 0) { psum[blk] = s; pmax[blk] = m4; }
    }
}

// ---------------------------------------------------------------- K6: merge partials + rmsnorm + W_out
__global__ __launch_bounds__(256) void k_out(
    const float* __restrict__ ppool, const float* __restrict__ psum,
    const float* __restrict__ pmax, const float* __restrict__ onw,
    const float* __restrict__ W_out, float* __restrict__ out, int t)
{
    __shared__ float pn[2][64];
    int tid = threadIdx.x;
    if (tid < 128) {
        int b = tid >> 6, d = tid & 63;
        float gm = -1e30f;
#pragma unroll 8
        for (int i = 0; i < 64; i++) gm = fmaxf(gm, pmax[b * 64 + i]);
        float s = 0.f, v = 0.f;
#pragma unroll 4
        for (int i = 0; i < 64; i++) {
            float e = __expf(pmax[b * 64 + i] - gm);
            s += psum[b * 64 + i] * e;
            v += ppool[(b * 64 + i) * 64 + d] * e;
        }
        float val = v / s;
        float ss = wave_sum(val * val);
        float rs = rsqrtf(ss * (1.0f / DS) + 1e-6f);
        pn[b][d] = onw[d] * val * rs;
    }
    __syncthreads();
    int b2 = tid >> 7, o0 = (tid & 127) * 2;
#pragma unroll
    for (int k = 0; k < 2; k++) {
        int o = o0 + k;
        const float* wr = W_out + o * DS;
        float a = 0.f;
#pragma unroll
        for (int d = 0; d < DS; d++) a += pn[b2][d] * wr[d];
        out[(b2 * TT + t) * DI + o] = a;
    }
}

// ----------------------------------------------------------------
extern "C" void kernel_launch(void* const* d_in, const int* in_sizes, int n_in,
                              void* d_out, int out_size, void* d_ws, size_t ws_size,
                              hipStream_t stream)
{
    const float* x          = (const float*)d_in[0];
    const float* W_in       = (const float*)d_in[1];
    const float* core_norm_w= (const float*)d_in[2];
    const float* core_Wg    = (const float*)d_in[3];
    const float* core_Wout  = (const float*)d_in[4];
    const float* W_gate     = (const float*)d_in[5];
    const float* W_vote     = (const float*)d_in[6];
    const float* attn_in_w  = (const float*)d_in[7];
    const float* attn_out_w = (const float*)d_in[8];
    const float* Wfs        = (const float*)d_in[9];
    const float* Wfsh       = (const float*)d_in[10];
    const float* query      = (const float*)d_in[11];
    const float* onw        = (const float*)d_in[12];
    const float* W_out      = (const float*)d_in[13];
    float* out = (float*)d_out;

    float* ws = (float*)d_ws;
    float* h        = ws;                              // 262144
    float* gate     = h + (size_t)BB * NN * DS;        // 4096
    float* xproj    = gate + BB * NN;                  // 128
    int*   col2slot = (int*)(xproj + BB * DS);         // 4096
    int*   act_idx  = col2slot + BB * NN;              // 1024
    float* u_g      = (float*)(act_idx + BB * KK);     // 262144
    float* part     = u_g + 256 * 1024;                // 262144
    float* qh       = part + 256 * 1024;               // 65536
    float* kh       = qh + BB * HH * KK * HD;
    float* vh       = kh + BB * HH * KK * HD;
    float* m_raw    = vh + BB * HH * KK * HD;          // 65536
    float* fsm      = m_raw + BB * DV * KK;            // 128
    float* fshm     = fsm + BB * DS;                   // 128
    float* ppool    = fshm + BB * DS;                  // 8192
    float* psum     = ppool + 128 * 64;                // 128
    float* pmax     = psum + 128;                      // 128

    hipMemsetAsync(h, 0, ((size_t)BB * NN * DS + BB * NN) * sizeof(float), stream);

    for (int t = 0; t < TT; t++) {
        k_topk<<<BB, 1024, 0, stream>>>(gate, x, W_in, col2slot, act_idx, xproj, t);
        k_core_a<<<256, 256, 0, stream>>>(h, xproj, act_idx, core_norm_w, core_Wg, u_g);
        k_hupd<<<64, 256, 0, stream>>>(u_g, core_Wout, part);
        k_vqkv<<<32, 256, 0, stream>>>(h, part, act_idx, W_vote, attn_in_w, qh, kh, vh);
        k_attn<<<BB * HH * KK / 4, 256, 0, stream>>>(qh, kh, vh, m_raw);
        k_film<<<18, 256, 0, stream>>>(h, act_idx, m_raw, vh, attn_out_w, Wfs, Wfsh, fsm, fshm);
        k_pool2<<<128, 256, 0, stream>>>(h, col2slot, fsm, fshm, query, W_gate, gate, ppool, psum, pmax);
        k_out<<<1, 256, 0, stream>>>(ppool, psum, pmax, onw, W_out, out, t);
    }
}